// Round 5
// baseline (109.965 us; speedup 1.0000x reference)
//
#include <hip/hip_runtime.h>

constexpr int FIELD = 26;
constexpr int EDIM  = 32;
constexpr int NPAIR = 325;   // C(26,2)
constexpr int BT    = 16;    // batch rows per block
constexpr int PG    = 8;     // pairs per group (1 pair per wave, 8 waves)
constexpr int NGRP  = (NPAIR + PG - 1) / PG;   // 41 (last group has 5 pairs)

typedef __bf16 bf16x8 __attribute__((ext_vector_type(8)));
typedef float  f32x4  __attribute__((ext_vector_type(4)));

static __device__ inline bf16x8 cvt8(const float4 a, const float4 b) {
    bf16x8 r;
    r[0] = (__bf16)a.x; r[1] = (__bf16)a.y; r[2] = (__bf16)a.z; r[3] = (__bf16)a.w;
    r[4] = (__bf16)b.x; r[5] = (__bf16)b.y; r[6] = (__bf16)b.z; r[7] = (__bf16)b.w;
    return r;
}

__global__ __launch_bounds__(512) void bilinear_rowstream(
    const float* __restrict__ x,     // [B][26][32]
    const float* __restrict__ W,     // [325][32][32]  W[p][e][d]
    const float* __restrict__ bias,  // [325][32]
    float* __restrict__ out)         // [B][325][32]
{
    const int tid = threadIdx.x;
    const int w   = tid >> 6;        // wave 0..7 -> pair within group
    const int l   = tid & 63;
    const int lr  = l & 15;          // MFMA col = batch row within tile
    const int g   = l >> 4;          // k-group / e-quad group

    const int b0  = blockIdx.x * BT;
    const float* xrow = x + (size_t)(b0 + lr) * FIELD * EDIM;   // this lane's batch row

    // staging: [buf][row(16)][pair(8)][f4col(8)], f4col XOR-swizzled by row&7
    __shared__ float4 stage[2][BT * PG * 8];   // 2 x 16 KB

    for (int grp = 0; grp < NGRP; ++grp) {
        const int pg0 = grp * PG;
        const int p   = pg0 + w;

        if (p < NPAIR) {
            // decode triu pair p -> (fi, fj); wave-uniform
            int fi = 0, rem = p;
            #pragma unroll 1
            while (rem >= FIELD - 1 - fi) { rem -= FIELD - 1 - fi; ++fi; }
            const int fj = fi + 1 + rem;

            // xi fragment: x[b][fi][g*8 .. +7]
            const float* xp = xrow + fi * EDIM + g * 8;
            const bf16x8 xf = cvt8(*(const float4*)xp, *(const float4*)(xp + 4));

            #pragma unroll
            for (int n = 0; n < 2; ++n) {
                // W fragment: W[p][n*16+lr][g*8 .. +7]  (L2-resident)
                const float* wp = W + ((size_t)p * EDIM + n * 16 + lr) * EDIM + g * 8;
                const bf16x8 wf = cvt8(*(const float4*)wp, *(const float4*)(wp + 4));

                const f32x4 acc = __builtin_amdgcn_mfma_f32_16x16x32_bf16(
                    wf, xf, (f32x4){0.f, 0.f, 0.f, 0.f}, 0, 0, 0);

                // lane holds D[e][b]: e = n*16 + g*4 + reg, b = b0 + lr
                const int e0 = n * 16 + g * 4;
                const float4 b4  = *(const float4*)(bias + (size_t)p * EDIM + e0);
                const float4 xj4 = *(const float4*)(xrow + fj * EDIM + e0);
                float4 r;
                r.x = (acc[0] + b4.x) * xj4.x;
                r.y = (acc[1] + b4.y) * xj4.y;
                r.z = (acc[2] + b4.z) * xj4.z;
                r.w = (acc[3] + b4.w) * xj4.w;

                const int c = (n * 4 + g) ^ (lr & 7);           // swizzled f4 column
                stage[grp & 1][(lr * PG + w) * 8 + c] = r;
            }
        }

        __syncthreads();   // one sync per group; double buffer makes the ring safe

        // store sweep: 16 KB, consecutive lanes -> consecutive global bytes.
        // per wave-instruction: 64 lanes x 16 B = 1 KB fully contiguous (one row-chunk)
        const float4* sb = stage[grp & 1];
        #pragma unroll
        for (int k = 0; k < 2; ++k) {
            const int slot = k * 512 + tid;      // f4 slot in group chunk
            const int row  = slot >> 6;          // 64 f4 per row-chunk (8 pairs * 128 B)
            const int po   = slot & 63;
            const int pp   = po >> 3;            // pair within group
            const int cc   = po & 7;             // f4 column
            if (pg0 + pp < NPAIR) {
                const float4 v = sb[(row * PG + pp) * 8 + (cc ^ (row & 7))];
                *(float4*)(out + (((size_t)(b0 + row)) * NPAIR + pg0 + pp) * EDIM + cc * 4) = v;
            }
        }
    }
}

extern "C" void kernel_launch(void* const* d_in, const int* in_sizes, int n_in,
                              void* d_out, int out_size, void* d_ws, size_t ws_size,
                              hipStream_t stream) {
    const float* x    = (const float*)d_in[0];
    const float* W    = (const float*)d_in[1];
    const float* bias = (const float*)d_in[2];
    float* out        = (float*)d_out;

    const int B = in_sizes[0] / (FIELD * EDIM);   // 4096
    dim3 grid(B / BT);                             // 256 blocks: batch-major, no pair dim
    bilinear_rowstream<<<grid, dim3(512), 0, stream>>>(x, W, bias, out);
}

// Round 6
// 88.573 us; speedup vs baseline: 1.2415x; 1.2415x over previous
//
#include <hip/hip_runtime.h>

constexpr int FIELD = 26;
constexpr int EDIM  = 32;
constexpr int NPAIR = 325;             // C(26,2)
constexpr int BT    = 16;              // batch rows per block
constexpr int PQ    = 5;               // pair quintiles (blocks per batch tile)
constexpr int PPB   = NPAIR / PQ;      // 65 pairs per block
constexpr int PG    = 4;               // pairs per group (1 per wave)
constexpr int NGRP  = (PPB + PG - 1) / PG;   // 17 (last group: 1 pair)

typedef __bf16 bf16x8 __attribute__((ext_vector_type(8)));
typedef float  f32x4  __attribute__((ext_vector_type(4)));

static __device__ inline bf16x8 cvt8(const float4 a, const float4 b) {
    bf16x8 r;
    r[0] = (__bf16)a.x; r[1] = (__bf16)a.y; r[2] = (__bf16)a.z; r[3] = (__bf16)a.w;
    r[4] = (__bf16)b.x; r[5] = (__bf16)b.y; r[6] = (__bf16)b.z; r[7] = (__bf16)b.w;
    return r;
}

__global__ __launch_bounds__(256, 5) void bilinear_stream5(
    const float* __restrict__ x,     // [B][26][32]
    const float* __restrict__ W,     // [325][32][32]  W[p][e][d]
    const float* __restrict__ bias,  // [325][32]
    float* __restrict__ out)         // [B][325][32]
{
    const int tid = threadIdx.x;
    const int w   = tid >> 6;        // wave 0..3 -> pair within group
    const int l   = tid & 63;
    const int lr  = l & 15;          // MFMA col = batch row within tile
    const int g   = l >> 4;          // k-group / e-quad group

    const int b0    = blockIdx.x * BT;      // batch tile (fast dim -> tiles spread over CUs)
    const int pbase = blockIdx.y * PPB;     // pair quintile (slow dim -> same-tile blocks co-resident)

    const float* xrow = x + (size_t)(b0 + lr) * FIELD * EDIM;

    // staging: [buf][row(16)][pair(4)][f4col(8)], f4col XOR-swizzled by row&7
    __shared__ float4 stage[2][BT * PG * 8];   // 2 x 8 KB

    // decode this wave's first pair (pbase + w), then walk by PG per group
    int fi = 0, fj;
    {
        int rem = pbase + w;
        #pragma unroll 1
        while (rem >= FIELD - 1 - fi) { rem -= FIELD - 1 - fi; ++fi; }
        fj = fi + 1 + rem;
    }

    for (int grp = 0; grp < NGRP; ++grp) {
        const int pg0   = grp * PG;
        const bool valid = (pg0 + w) < PPB;
        const int p     = pbase + pg0 + w;

        if (valid) {
            // xi fragment: x[b][fi][g*8 .. +7]
            const float* xp = xrow + fi * EDIM + g * 8;
            const bf16x8 xf = cvt8(*(const float4*)xp, *(const float4*)(xp + 4));

            #pragma unroll
            for (int n = 0; n < 2; ++n) {
                // W fragment: W[p][n*16+lr][g*8 .. +7]  (L2-resident)
                const float* wp = W + ((size_t)p * EDIM + n * 16 + lr) * EDIM + g * 8;
                const bf16x8 wf = cvt8(*(const float4*)wp, *(const float4*)(wp + 4));

                const f32x4 acc = __builtin_amdgcn_mfma_f32_16x16x32_bf16(
                    wf, xf, (f32x4){0.f, 0.f, 0.f, 0.f}, 0, 0, 0);

                // lane holds D[e][b]: e = n*16 + g*4 + reg, b = b0 + lr
                const int e0 = n * 16 + g * 4;
                const float4 b4  = *(const float4*)(bias + (size_t)p * EDIM + e0);
                const float4 xj4 = *(const float4*)(xrow + fj * EDIM + e0);
                float4 r;
                r.x = (acc[0] + b4.x) * xj4.x;
                r.y = (acc[1] + b4.y) * xj4.y;
                r.z = (acc[2] + b4.z) * xj4.z;
                r.w = (acc[3] + b4.w) * xj4.w;

                const int c = (n * 4 + g) ^ (lr & 7);           // swizzled f4 column
                stage[grp & 1][(lr * PG + w) * 8 + c] = r;
            }
        }

        // advance (fi, fj) by PG pairs for next group (wave-uniform)
        #pragma unroll
        for (int s = 0; s < PG; ++s) {
            if (++fj == FIELD) { ++fi; fj = fi + 1; }
        }

        __syncthreads();   // double buffer: one barrier per group is hazard-free

        // store sweep: 8 KB, 512-B contiguous segments per row, 2 f4 per thread
        const float4* sb = stage[grp & 1];
        #pragma unroll
        for (int k = 0; k < 2; ++k) {
            const int slot = k * 256 + tid;      // f4 slot in group chunk
            const int row  = slot >> 5;          // 32 f4 per row-chunk (4 pairs * 128 B)
            const int po   = slot & 31;
            const int pp   = po >> 3;            // pair within group
            const int cc   = po & 7;             // f4 column
            if (pg0 + pp < PPB) {
                const float4 v = sb[(row * PG + pp) * 8 + (cc ^ (row & 7))];
                *(float4*)(out + (((size_t)(b0 + row)) * NPAIR + pbase + pg0 + pp) * EDIM + cc * 4) = v;
            }
        }
    }
}

extern "C" void kernel_launch(void* const* d_in, const int* in_sizes, int n_in,
                              void* d_out, int out_size, void* d_ws, size_t ws_size,
                              hipStream_t stream) {
    const float* x    = (const float*)d_in[0];
    const float* W    = (const float*)d_in[1];
    const float* bias = (const float*)d_in[2];
    float* out        = (float*)d_out;

    const int B = in_sizes[0] / (FIELD * EDIM);   // 4096
    dim3 grid(B / BT, PQ);                         // x fast: same-tile quintiles land together
    bilinear_stream5<<<grid, dim3(256), 0, stream>>>(x, W, bias, out);
}

// Round 8
// 75.146 us; speedup vs baseline: 1.4634x; 1.1787x over previous
//
#include <hip/hip_runtime.h>

constexpr int FIELD = 26;
constexpr int EDIM  = 32;
constexpr int NPAIR = 325;   // C(26,2)
constexpr int BT    = 16;    // batch rows per wave-tile

typedef __bf16 bf16x8 __attribute__((ext_vector_type(8)));
typedef float  f32x4  __attribute__((ext_vector_type(4)));

static __device__ inline bf16x8 cvt8(const float4 a, const float4 b) {
    bf16x8 r;
    r[0] = (__bf16)a.x; r[1] = (__bf16)a.y; r[2] = (__bf16)a.z; r[3] = (__bf16)a.w;
    r[4] = (__bf16)b.x; r[5] = (__bf16)b.y; r[6] = (__bf16)b.z; r[7] = (__bf16)b.w;
    return r;
}

__global__ __launch_bounds__(256, 4) void bilinear_persist(
    const float* __restrict__ x,     // [B][26][32]
    const float* __restrict__ W,     // [325][32][32]  W[p][e][d]
    const float* __restrict__ bias,  // [325][32]
    float* __restrict__ out,         // [B][325][32]
    int ntiles)                      // (B/BT)*NPAIR
{
    // wave-private transpose stage: [wave][row][f4col], col XOR-swizzled by row&7
    __shared__ float4 stage[4][BT][8];   // 8 KB / block

    const int tid = threadIdx.x;
    const int w   = tid >> 6;        // wave 0..3
    const int l   = tid & 63;
    const int lr  = l & 15;          // MFMA col = batch row in tile
    const int g   = l >> 4;          // k-group / e-quad group
    const int bq  = l >> 3;          // store phase: row base 0..7
    const int eq  = l & 7;           // store phase: e-quad 0..7

    const int stride = gridDim.x * 4;

    for (int idx = blockIdx.x * 4 + w; idx < ntiles; idx += stride) {
        // idx = bt*NPAIR + p  (p fastest: dense moving write window)
        const int bt = (int)(((unsigned long long)(unsigned)idx * 13215284ull) >> 32); // exact /325
        const int p  = idx - bt * NPAIR;
        const int b0 = bt * BT;

        // decode triu pair p -> (fi, fj); wave-uniform
        int fi = 0, rem = p;
        #pragma unroll 1
        while (rem >= FIELD - 1 - fi) { rem -= FIELD - 1 - fi; ++fi; }
        const int fj = fi + 1 + rem;

        // ---- MFMA-input loads (issue first)
        const float* xp = x + ((size_t)(b0 + lr) * FIELD + fi) * EDIM + g * 8;
        const float4 xa = *(const float4*)xp;
        const float4 xb = *(const float4*)(xp + 4);
        float4 wlo[2], whi[2];
        #pragma unroll
        for (int n = 0; n < 2; ++n) {
            const float* wp = W + ((size_t)p * EDIM + n * 16 + lr) * EDIM + g * 8;
            wlo[n] = *(const float4*)wp;
            whi[n] = *(const float4*)(wp + 4);
        }
        // ---- epilogue loads (post-transpose addressing; fully coalesced)
        const float4 b4 = *(const float4*)(bias + (size_t)p * EDIM + eq * 4);
        float4 xj4[2];
        #pragma unroll
        for (int s = 0; s < 2; ++s)
            xj4[s] = *(const float4*)(x + ((size_t)(b0 + bq + 8 * s) * FIELD + fj) * EDIM + eq * 4);

        // ---- compute: D[e][b], lane holds b = b0+lr, e = n*16 + g*4 + reg
        const bf16x8 xf = cvt8(xa, xb);
        #pragma unroll
        for (int n = 0; n < 2; ++n) {
            const f32x4 acc = __builtin_amdgcn_mfma_f32_16x16x32_bf16(
                cvt8(wlo[n], whi[n]), xf, (f32x4){0.f, 0.f, 0.f, 0.f}, 0, 0, 0);
            float4 v; v.x = acc[0]; v.y = acc[1]; v.z = acc[2]; v.w = acc[3];
            stage[w][lr][(n * 4 + g) ^ (lr & 7)] = v;   // wave-local, conflict-free
        }

        // ---- wave-local transpose read + epilogue + 128 B-segment stores
        #pragma unroll
        for (int s = 0; s < 2; ++s) {
            const int row = bq + 8 * s;
            const float4 t = stage[w][row][eq ^ (row & 7)];
            f32x4 r;
            r[0] = (t.x + b4.x) * xj4[s].x;
            r[1] = (t.y + b4.y) * xj4[s].y;
            r[2] = (t.z + b4.z) * xj4[s].z;
            r[3] = (t.w + b4.w) * xj4[s].w;
            f32x4* dst = (f32x4*)(out + ((size_t)(b0 + row) * NPAIR + p) * EDIM + eq * 4);
            __builtin_nontemporal_store(r, dst);   // write-once full-line stream
        }
    }
}

extern "C" void kernel_launch(void* const* d_in, const int* in_sizes, int n_in,
                              void* d_out, int out_size, void* d_ws, size_t ws_size,
                              hipStream_t stream) {
    const float* x    = (const float*)d_in[0];
    const float* W    = (const float*)d_in[1];
    const float* bias = (const float*)d_in[2];
    float* out        = (float*)d_out;

    const int B      = in_sizes[0] / (FIELD * EDIM);   // 4096
    const int ntiles = (B / BT) * NPAIR;               // 83200
    bilinear_persist<<<dim3(1024), dim3(256), 0, stream>>>(x, W, bias, out, ntiles);
}